// Round 1
// baseline (380.253 us; speedup 1.0000x reference)
//
#include <hip/hip_runtime.h>

#define N_NODES 100000
#define N_EDGES 20000
#define N_INC   800000
#define D_IN    256
#define D_H     16
#define D_OUT   40

// fixed-capacity padded buckets, filled by direct atomic scatter.
// edge degree ~ Poisson(40): max over 20k bins ~ 68  -> ECAP 128 (+14 sigma)
// node degree ~ Poisson(8):  max over 100k bins ~ 22 -> VCAP 32  (+8.5 sigma)
#define ECAP 128
#define VCAP 32

#define GEMM_BLOCKS 1563   // ceil((N_NODES/16 waves)/4)
#define SCAT_BLOCKS 3125   // N_INC / 256

typedef short bf16x8 __attribute__((ext_vector_type(8)));
typedef float f32x4  __attribute__((ext_vector_type(4)));

__device__ __forceinline__ unsigned short f2bf(float f) {
    unsigned u = __float_as_uint(f);
    unsigned r = u + 0x7FFF + ((u >> 16) & 1);   // round-to-nearest-even
    return (unsigned short)(r >> 16);
}

// ---------------- K0: pack W1 into MFMA B-frag layout; zero bucket counters ----
// B-frag for chunk c, lane l: 8 bf16 = W1[c*32 + (l>>4)*8 + j][l&15], j=0..7
__global__ __launch_bounds__(512) void init_kernel(
    const float* __restrict__ W1, unsigned short* __restrict__ bfrag,
    int* __restrict__ cnts /* cnt_e(20000) ++ cnt_v(100000) */) {
    int g = blockIdx.x * 512 + threadIdx.x;
    for (int i = g; i < N_EDGES + N_NODES; i += gridDim.x * 512) cnts[i] = 0;
    if (blockIdx.x == 0) {
        int t = threadIdx.x;
        int c = t >> 6, l = t & 63;      // 512 threads = 8 chunks x 64 lanes
        int n = l & 15, q = l >> 4;
        unsigned short v[8];
#pragma unroll
        for (int j = 0; j < 8; ++j)
            v[j] = f2bf(W1[(c * 32 + q * 8 + j) * D_H + n]);
        *(int4*)(bfrag + (size_t)(c * 64 + l) * 8) = *(int4*)v;
    }
}

// ---------------- K1: fused  T = H @ W1 (MFMA)  ||  incidence bucket scatter ---
// gemm blocks first (long pole, HBM streaming); scatter blocks fill in around it.
__global__ __launch_bounds__(256) void gemm_scatter_kernel(
    const float* __restrict__ H, const unsigned short* __restrict__ bfrag,
    float* __restrict__ T,
    const int* __restrict__ ni, const int* __restrict__ ei,
    const float* __restrict__ w,
    int* __restrict__ cnt_e, int* __restrict__ cnt_v,
    int2* __restrict__ staged_e, int* __restrict__ staged_v) {
    if (blockIdx.x < GEMM_BLOCKS) {
        int wave = (blockIdx.x * 256 + threadIdx.x) >> 6;
        if (wave >= N_NODES / 16) return;        // wave-uniform guard
        int lane = threadIdx.x & 63;
        int m = lane & 15, q = lane >> 4;
        int row0 = wave * 16;
        const float* hp = H + (size_t)(row0 + m) * D_IN + q * 8;

        bf16x8 bf[8];
        const int4* bp = (const int4*)bfrag;
#pragma unroll
        for (int c = 0; c < 8; ++c) {
            int4 raw = bp[c * 64 + lane];
            bf[c] = *(bf16x8*)&raw;
        }
        f32x4 acc = {0.f, 0.f, 0.f, 0.f};
#pragma unroll
        for (int c = 0; c < 8; ++c) {
            float4 lo = *(const float4*)(hp + c * 32);
            float4 hi = *(const float4*)(hp + c * 32 + 4);
            bf16x8 af;
            af[0] = f2bf(lo.x); af[1] = f2bf(lo.y); af[2] = f2bf(lo.z); af[3] = f2bf(lo.w);
            af[4] = f2bf(hi.x); af[5] = f2bf(hi.y); af[6] = f2bf(hi.z); af[7] = f2bf(hi.w);
            acc = __builtin_amdgcn_mfma_f32_16x16x32_bf16(af, bf[c], acc, 0, 0, 0);
        }
        // C/D layout: col = lane&15, row = q*4 + reg
#pragma unroll
        for (int r = 0; r < 4; ++r)
            T[(size_t)(row0 + q * 4 + r) * D_H + m] = acc[r];
    } else {
        int i = (blockIdx.x - GEMM_BLOCKS) * 256 + threadIdx.x;
        if (i < N_INC) {
            int v = ni[i], e = ei[i];
            float wv = w[v];
            int pe = atomicAdd(&cnt_e[e], 1);
            if (pe < ECAP)
                staged_e[(size_t)e * ECAP + pe] = make_int2(v, __float_as_int(wv));
            int pv = atomicAdd(&cnt_v[v], 1);
            if (pv < VCAP)
                staged_v[v * VCAP + pv] = e;
        }
    }
}

// ---------------- gatherA: node -> edge, one wave per edge ----------------------
__global__ __launch_bounds__(256) void gatherA_kernel(
    const int* __restrict__ cnt_e, const int2* __restrict__ staged_e,
    const float* __restrict__ X, float* __restrict__ e_feat) {
    int e = (blockIdx.x * 256 + threadIdx.x) >> 6;
    if (e >= N_EDGES) return;
    int lane = threadIdx.x & 63;
    int s = lane >> 4, j = lane & 15;
    int cnt = min(cnt_e[e], ECAP);
    const int2* rp = staged_e + (size_t)e * ECAP;
    float acc = 0.f, den = 0.f;
    for (int k = s; k < cnt; k += 4) {
        int2 rec = rp[k];
        float wv = __int_as_float(rec.y);
        acc += X[rec.x * D_H + j] * wv;
        den += wv;
    }
    acc += __shfl_xor(acc, 16, 64);  den += __shfl_xor(den, 16, 64);
    acc += __shfl_xor(acc, 32, 64);  den += __shfl_xor(den, 32, 64);
    if (s == 0) e_feat[e * D_H + j] = acc / fmaxf(den, 1e-6f);
}

// ---------------- gatherB layer 1: edge -> node, relu(mean+b1) ------------------
__global__ __launch_bounds__(256) void gatherB1_kernel(
    const int* __restrict__ cnt_v, const int* __restrict__ staged_v,
    const float* __restrict__ e_feat,
    const float* __restrict__ b1, float* __restrict__ out) {
    int t = blockIdx.x * 256 + threadIdx.x;
    int n = t >> 4;
    if (n >= N_NODES) return;
    int j = t & 15;
    int cnt = min(cnt_v[n], VCAP);
    const int* rp = staged_v + n * VCAP;
    float acc = 0.f;
    for (int k = 0; k < cnt; ++k)
        acc += e_feat[rp[k] * D_H + j];
    float inv = 1.f / fmaxf((float)cnt, 1.f);
    out[n * D_H + j] = fmaxf(acc * inv + b1[j], 0.f);
}

// ---------------- gatherB layer 2 + matmul + log_softmax fused ------------------
// 256 threads = 16 nodes x 16 lanes. Phase 1: mean over edges -> y in LDS.
// Phase 2: lane j of node computes z_c for c in {j, j+16, j+32<40}; shuffle
// softmax over the 16-lane group; writes out directly.
__global__ __launch_bounds__(256) void gatherB2_final_kernel(
    const int* __restrict__ cnt_v, const int* __restrict__ staged_v,
    const float* __restrict__ e_feat,
    const float* __restrict__ W2, const float* __restrict__ b2,
    float* __restrict__ out) {
    __shared__ float sy[16 * 17];
    __shared__ float sW2[D_H * D_OUT];
    __shared__ float sb2[D_OUT];
    int t = threadIdx.x;
    for (int i = t; i < D_H * D_OUT; i += 256) sW2[i] = W2[i];
    if (t < D_OUT) sb2[t] = b2[t];
    int nl = t >> 4, j = t & 15;
    int n = blockIdx.x * 16 + nl;
    float y = 0.f;
    if (n < N_NODES) {
        int cnt = min(cnt_v[n], VCAP);
        const int* rp = staged_v + n * VCAP;
        float acc = 0.f;
        for (int k = 0; k < cnt; ++k)
            acc += e_feat[rp[k] * D_H + j];
        y = acc / fmaxf((float)cnt, 1.f);
    }
    sy[nl * 17 + j] = y;
    __syncthreads();
    if (n >= N_NODES) return;
    // z for c = j, j+16, (j+32 if j<8)
    float z0 = sb2[j], z1 = sb2[j + 16];
    float z2 = (j < 8) ? sb2[j + 32] : -1e30f;
#pragma unroll
    for (int jj = 0; jj < D_H; ++jj) {
        float yy = sy[nl * 17 + jj];
        z0 += yy * sW2[jj * D_OUT + j];
        z1 += yy * sW2[jj * D_OUT + j + 16];
        if (j < 8) z2 += yy * sW2[jj * D_OUT + j + 32];
    }
    float m = fmaxf(fmaxf(z0, z1), z2);
#pragma unroll
    for (int o = 1; o < 16; o <<= 1) m = fmaxf(m, __shfl_xor(m, o, 64));
    float se = __expf(z0 - m) + __expf(z1 - m) + ((j < 8) ? __expf(z2 - m) : 0.f);
#pragma unroll
    for (int o = 1; o < 16; o <<= 1) se += __shfl_xor(se, o, 64);
    float lse = m + __logf(se);
    float* o = out + (size_t)n * D_OUT;
    o[j] = z0 - lse;
    o[j + 16] = z1 - lse;
    if (j < 8) o[j + 32] = z2 - lse;
}

extern "C" void kernel_launch(void* const* d_in, const int* in_sizes, int n_in,
                              void* d_out, int out_size, void* d_ws, size_t ws_size,
                              hipStream_t stream) {
    const float* H  = (const float*)d_in[0];
    const float* w  = (const float*)d_in[1];
    const int*   ni = (const int*)d_in[2];
    const int*   ei = (const int*)d_in[3];
    const float* W1 = (const float*)d_in[4];
    const float* b1 = (const float*)d_in[5];
    const float* W2 = (const float*)d_in[6];
    const float* b2 = (const float*)d_in[7];
    float* out = (float*)d_out;

    // workspace layout (4-byte words)
    int*            ws_i     = (int*)d_ws;
    int*            cnt_e    = ws_i + 0;                      // 20,000
    int*            cnt_v    = ws_i + 20000;                  // 100,000
    unsigned short* bfrag    = (unsigned short*)(ws_i + 120000);  // 4096 ush
    int2*           staged_e = (int2*)(ws_i + 122048);        // 20000*128 int2
    int*            staged_v = ws_i + 5242048;                // 100000*32
    float*          T        = (float*)(ws_i + 8442048);      // 1,600,000
    float*          e_feat   = (float*)(ws_i + 10042048);     // 320,000
    float*          x1       = (float*)(ws_i + 10362048);     // 1,600,000
    // total 11,962,048 words = 47.8 MB

    init_kernel<<<128, 512, 0, stream>>>(W1, bfrag, cnt_e);

    gemm_scatter_kernel<<<GEMM_BLOCKS + SCAT_BLOCKS, 256, 0, stream>>>(
        H, bfrag, T, ni, ei, w, cnt_e, cnt_v, staged_e, staged_v);

    const int gA_grid = (N_EDGES * 64 + 255) / 256;
    const int gB_grid = (N_NODES * 16 + 255) / 256;

    // layer 1
    gatherA_kernel<<<gA_grid, 256, 0, stream>>>(cnt_e, staged_e, T, e_feat);
    gatherB1_kernel<<<gB_grid, 256, 0, stream>>>(cnt_v, staged_v, e_feat, b1, x1);
    // layer 2 (+ final matmul + log_softmax fused)
    gatherA_kernel<<<gA_grid, 256, 0, stream>>>(cnt_e, staged_e, x1, e_feat);
    gatherB2_final_kernel<<<(N_NODES + 15) / 16, 256, 0, stream>>>(
        cnt_v, staged_v, e_feat, W2, b2, out);
}